// Round 6
// baseline (318.365 us; speedup 1.0000x reference)
//
#include <hip/hip_runtime.h>
#include <hip/hip_bf16.h>

typedef __bf16 bf16;
typedef __bf16 bf16x8 __attribute__((ext_vector_type(8)));
typedef float f32x4 __attribute__((ext_vector_type(4)));

#define B_   4
#define T_   2048
#define DM_  1024
#define DH_  1024
#define MROWS 8192

// ---------------------------------------------------------------------------
// fp32 -> bf16 for the four weight matrices only (16 MB read, 8 MB write).
// Activations are converted inside the QKV GEMM's staging (register-
// prefetched, see gemm_f32a).
// ---------------------------------------------------------------------------
struct CvtJob { const float* src; bf16* dst; int nf4; };
struct CvtArgs { CvtJob job[4]; };

__global__ __launch_bounds__(256) void cvt_kernel(CvtArgs args) {
  CvtJob jb = args.job[blockIdx.y];
  int base = blockIdx.x * 2048;
  if (base >= jb.nf4) return;
  int t2 = threadIdx.x * 2;
  const float4* s = (const float4*)jb.src;
  float4 a[4][2];
#pragma unroll
  for (int u = 0; u < 4; ++u) {
    a[u][0] = s[base + u * 512 + t2];
    a[u][1] = s[base + u * 512 + t2 + 1];
  }
#pragma unroll
  for (int u = 0; u < 4; ++u) {
    bf16x8 o;
    o[0] = (bf16)a[u][0].x; o[1] = (bf16)a[u][0].y;
    o[2] = (bf16)a[u][0].z; o[3] = (bf16)a[u][0].w;
    o[4] = (bf16)a[u][1].x; o[5] = (bf16)a[u][1].y;
    o[6] = (bf16)a[u][1].z; o[7] = (bf16)a[u][1].w;
    *(bf16x8*)(jb.dst + ((size_t)base + u * 512 + t2) * 4) = o;
  }
}

// ---------------------------------------------------------------------------
// QKV GEMM with fp32 A fused conversion: C = A[M,K](fp32) * B[N,K]^T(bf16).
// m97 tile structure (128x128, BK=64, 4 waves, 4x4 MFMA 16x16x32, XOR-
// swizzled LDS). Key difference from r3's FAILED sync version: A-tile loads
// are REGISTER-PREFETCHED one K-iter ahead — issued after the mid-iter
// barrier, so they fly across the MFMA block + end barrier instead of being
// drained cold at point of use. B stays async global_load_lds (L2-hot
// weights). Epilogue mode: 1 = bf16(sigmoid(acc)); 2 = bf16(acc).
// XCD swizzle as in r5 (gridDim.x==8, gridDim.y%8==0).
// ---------------------------------------------------------------------------
struct GemmF32Job { const float* A; const bf16* Bw; bf16* Cb; int mode; };
struct GemmF32Args { GemmF32Job job[3]; };

__global__ __launch_bounds__(256) void gemm_f32a(GemmF32Args ga) {
  const GemmF32Job jb = ga.job[blockIdx.z];
  const int N = DH_, K = DM_;
  __shared__ bf16 As[128 * 64];
  __shared__ bf16 Bs[128 * 64];

  const int tid  = threadIdx.x;
  const int lane = tid & 63;
  const int wave = tid >> 6;
  const int wm   = (wave >> 1) * 64;
  const int wn   = (wave & 1) * 64;

  const int f   = blockIdx.y * 8 + blockIdx.x;
  const int xcd = f & 7;
  const int j   = f >> 3;
  const int bn  = j & 7;
  const int bm  = (j >> 3) * 8 + xcd;
  const int tileM = bm * 128;
  const int tileN = bn * 128;

  f32x4 acc[4][4] = {};

  const int sr = lane >> 3;
  const int sc = (lane & 7) ^ sr;

  // Per-lane fp32 A source: row (wave*4+l)*8+sr, k-chunk sc (8 floats).
  const float* Abase = jb.A + (size_t)(tileM + wave * 32 + sr) * K + sc * 8;

  // prologue: preload A regs for k0=0 (only iter with exposed latency)
  float4 av[4][2];
#pragma unroll
  for (int l = 0; l < 4; ++l) {
    const float* p = Abase + (size_t)(l * 8) * K;
    av[l][0] = *(const float4*)p;
    av[l][1] = *(const float4*)(p + 4);
  }

  for (int i = 0; i < K / 64; ++i) {
    const int k0 = i * 64;
    // B staging (async DMA; drained by the barrier below)
#pragma unroll
    for (int l = 0; l < 4; ++l) {
      int grp = wave * 4 + l;
      int row = grp * 8 + sr;
      const bf16* gbadr = jb.Bw + (size_t)(tileN + row) * K + k0 + sc * 8;
      __builtin_amdgcn_global_load_lds(
          (const __attribute__((address_space(1))) void*)gbadr,
          (__attribute__((address_space(3))) void*)&Bs[grp * 512], 16, 0, 0);
    }
    // cvt prefetched A regs -> bf16 -> LDS (same slot global_load_lds used)
#pragma unroll
    for (int l = 0; l < 4; ++l) {
      bf16x8 w;
      w[0] = (bf16)av[l][0].x; w[1] = (bf16)av[l][0].y;
      w[2] = (bf16)av[l][0].z; w[3] = (bf16)av[l][0].w;
      w[4] = (bf16)av[l][1].x; w[5] = (bf16)av[l][1].y;
      w[6] = (bf16)av[l][1].z; w[7] = (bf16)av[l][1].w;
      *(bf16x8*)&As[(wave * 4 + l) * 512 + lane * 8] = w;
    }
    __syncthreads();

    // PREFETCH next A tile — issued before MFMA so the loads overlap it.
    if (i + 1 < K / 64) {
#pragma unroll
      for (int l = 0; l < 4; ++l) {
        const float* p = Abase + (size_t)(l * 8) * K + k0 + 64;
        av[l][0] = *(const float4*)p;
        av[l][1] = *(const float4*)(p + 4);
      }
    }

    const int quad = lane >> 4;
#pragma unroll
    for (int s = 0; s < 2; ++s) {
      bf16x8 af[4], bfr[4];
#pragma unroll
      for (int mt = 0; mt < 4; ++mt) {
        int row = wm + mt * 16 + (lane & 15);
        int chunk = (s * 4 + quad) ^ (row & 7);
        af[mt] = *(const bf16x8*)&As[row * 64 + chunk * 8];
      }
#pragma unroll
      for (int nt = 0; nt < 4; ++nt) {
        int row = wn + nt * 16 + (lane & 15);
        int chunk = (s * 4 + quad) ^ (row & 7);
        bfr[nt] = *(const bf16x8*)&Bs[row * 64 + chunk * 8];
      }
#pragma unroll
      for (int mt = 0; mt < 4; ++mt)
#pragma unroll
        for (int nt = 0; nt < 4; ++nt)
          acc[mt][nt] = __builtin_amdgcn_mfma_f32_16x16x32_bf16(
              af[mt], bfr[nt], acc[mt][nt], 0, 0, 0);
    }
    __syncthreads();
  }

  // epilogue: C/D layout col=lane&15, row=(lane>>4)*4+reg
  const int cn = lane & 15;
  const int cr = (lane >> 4) * 4;
  if (jb.mode == 1) {
#pragma unroll
    for (int mt = 0; mt < 4; ++mt)
#pragma unroll
      for (int nt = 0; nt < 4; ++nt)
#pragma unroll
        for (int r = 0; r < 4; ++r) {
          int row = tileM + wm + mt * 16 + cr + r;
          int col = tileN + wn + nt * 16 + cn;
          jb.Cb[(size_t)row * N + col] =
              (bf16)(1.f / (1.f + __expf(-acc[mt][nt][r])));
        }
  } else {
#pragma unroll
    for (int mt = 0; mt < 4; ++mt)
#pragma unroll
      for (int nt = 0; nt < 4; ++nt)
#pragma unroll
        for (int r = 0; r < 4; ++r) {
          int row = tileM + wm + mt * 16 + cr + r;
          int col = tileN + wn + nt * 16 + cn;
          jb.Cb[(size_t)row * N + col] = (bf16)acc[mt][nt][r];
        }
  }
}

// ---------------------------------------------------------------------------
// All-bf16 GEMM (out-projection): C[M,N] fp32 = A[M,K] * B[N,K]^T.
// Unchanged r5 structure (async global_load_lds both operands).
// ---------------------------------------------------------------------------
struct GemmJob { const bf16* A; const bf16* Bw; float* Cf; };
struct GemmArgs { GemmJob job[1]; int N; int K; };

__global__ __launch_bounds__(256) void gemm_bt(GemmArgs ga) {
  const GemmJob jb = ga.job[0];
  const int N = ga.N, K = ga.K;
  __shared__ bf16 As[128 * 64];
  __shared__ bf16 Bs[128 * 64];

  const int tid  = threadIdx.x;
  const int lane = tid & 63;
  const int wave = tid >> 6;
  const int wm   = (wave >> 1) * 64;
  const int wn   = (wave & 1) * 64;

  const int f   = blockIdx.y * 8 + blockIdx.x;
  const int xcd = f & 7;
  const int j   = f >> 3;
  const int bn  = j & 7;
  const int bm  = (j >> 3) * 8 + xcd;
  const int tileM = bm * 128;
  const int tileN = bn * 128;

  f32x4 acc[4][4] = {};

  const int sr = lane >> 3;
  const int sc = (lane & 7) ^ sr;

  for (int k0 = 0; k0 < K; k0 += 64) {
#pragma unroll
    for (int l = 0; l < 4; ++l) {
      int grp = wave * 4 + l;
      int row = grp * 8 + sr;
      const bf16* gaadr = jb.A + (size_t)(tileM + row) * K + k0 + sc * 8;
      __builtin_amdgcn_global_load_lds(
          (const __attribute__((address_space(1))) void*)gaadr,
          (__attribute__((address_space(3))) void*)&As[grp * 512], 16, 0, 0);
      const bf16* gbadr = jb.Bw + (size_t)(tileN + row) * K + k0 + sc * 8;
      __builtin_amdgcn_global_load_lds(
          (const __attribute__((address_space(1))) void*)gbadr,
          (__attribute__((address_space(3))) void*)&Bs[grp * 512], 16, 0, 0);
    }
    __syncthreads();

    const int quad = lane >> 4;
#pragma unroll
    for (int s = 0; s < 2; ++s) {
      bf16x8 af[4], bfr[4];
#pragma unroll
      for (int mt = 0; mt < 4; ++mt) {
        int row = wm + mt * 16 + (lane & 15);
        int chunk = (s * 4 + quad) ^ (row & 7);
        af[mt] = *(const bf16x8*)&As[row * 64 + chunk * 8];
      }
#pragma unroll
      for (int nt = 0; nt < 4; ++nt) {
        int row = wn + nt * 16 + (lane & 15);
        int chunk = (s * 4 + quad) ^ (row & 7);
        bfr[nt] = *(const bf16x8*)&Bs[row * 64 + chunk * 8];
      }
#pragma unroll
      for (int mt = 0; mt < 4; ++mt)
#pragma unroll
        for (int nt = 0; nt < 4; ++nt)
          acc[mt][nt] = __builtin_amdgcn_mfma_f32_16x16x32_bf16(
              af[mt], bfr[nt], acc[mt][nt], 0, 0, 0);
    }
    __syncthreads();
  }

  const int cn = lane & 15;
  const int cr = (lane >> 4) * 4;
#pragma unroll
  for (int mt = 0; mt < 4; ++mt)
#pragma unroll
    for (int nt = 0; nt < 4; ++nt)
#pragma unroll
      for (int r = 0; r < 4; ++r) {
        int row = tileM + wm + mt * 16 + cr + r;
        int col = tileN + wn + nt * 16 + cn;
        jb.Cf[(size_t)row * N + col] = acc[mt][nt][r];
      }
}

// ---------------------------------------------------------------------------
// Pass A: per-block partial reduction over 8 j-rows, atomic-free (r5-proven).
// ---------------------------------------------------------------------------
__global__ __launch_bounds__(256) void reduce_kv(
    const bf16* __restrict__ Kb, const bf16* __restrict__ Vb,
    float* __restrict__ part) {
  __shared__ float lds[64 * 128];
  const int t = threadIdx.x;
  const int half = t >> 7;
  const int dt = t & 127;
  const int d = dt * 8;
  const int j0 = blockIdx.x * 8 + half * 4;
  const size_t bs = (size_t)T_ * DH_;
  float n[4][8] = {}, e[4][8] = {};
#pragma unroll 2
  for (int jj = j0; jj < j0 + 4; ++jj) {
    size_t off = (size_t)jj * DH_ + d;
    bf16x8 kk[4], vv[4];
#pragma unroll
    for (int b = 0; b < 4; ++b) {
      kk[b] = *(const bf16x8*)(Kb + off + b * bs);
      vv[b] = *(const bf16x8*)(Vb + off + b * bs);
    }
#pragma unroll
    for (int c = 0; c < 8; ++c) {
      float k0 = (float)kk[0][c], k1 = (float)kk[1][c];
      float k2 = (float)kk[2][c], k3 = (float)kk[3][c];
      float m = fmaxf(fmaxf(k0, k1), fmaxf(k2, k3));
      float w0 = __expf(k0 - m), w1 = __expf(k1 - m);
      float w2 = __expf(k2 - m), w3 = __expf(k3 - m);
      e[0][c] += w0; e[1][c] += w1; e[2][c] += w2; e[3][c] += w3;
      n[0][c] += w0 * (float)vv[0][c];
      n[1][c] += w1 * (float)vv[1][c];
      n[2][c] += w2 * (float)vv[2][c];
      n[3][c] += w3 * (float)vv[3][c];
    }
  }
  if (half) {
#pragma unroll
    for (int b = 0; b < 4; ++b)
#pragma unroll
      for (int c = 0; c < 8; ++c) {
        lds[(b * 8 + c) * 128 + dt] = n[b][c];
        lds[(32 + b * 8 + c) * 128 + dt] = e[b][c];
      }
  }
  __syncthreads();
  if (!half) {
    float* po = part + (size_t)blockIdx.x * 8192;
#pragma unroll
    for (int b = 0; b < 4; ++b)
#pragma unroll
      for (int c = 0; c < 8; ++c) {
        po[b * 1024 + d + c] = n[b][c] + lds[(b * 8 + c) * 128 + dt];
        po[4096 + b * 1024 + d + c] = e[b][c] + lds[(32 + b * 8 + c) * 128 + dt];
      }
  }
}

// ---------------------------------------------------------------------------
// Pass B: numden[slot] = sum over 256 partial blocks (r5-proven).
// ---------------------------------------------------------------------------
__global__ __launch_bounds__(256) void finish_kv(
    const float* __restrict__ part, float* __restrict__ numden) {
  __shared__ float lds[128];
  const int t = threadIdx.x;
  const int half = t >> 7;
  const int sl = t & 127;
  const int slot = blockIdx.x * 128 + sl;
  float s = 0.f;
  for (int i = half * 128; i < half * 128 + 128; i += 8) {
#pragma unroll
    for (int u = 0; u < 8; ++u)
      s += part[(size_t)(i + u) * 8192 + slot];
  }
  if (half) lds[sl] = s;
  __syncthreads();
  if (!half) numden[slot] = s + lds[sl];
}

// ---------------------------------------------------------------------------
// Yb[i] *= num[b,h]/den[b,h]  (in place, bf16).
// ---------------------------------------------------------------------------
__global__ __launch_bounds__(256) void mul_ratio(
    bf16* __restrict__ Yb, const float* __restrict__ num,
    const float* __restrict__ den) {
  size_t i = ((size_t)blockIdx.x * 256 + threadIdx.x) * 8;
  int h = (int)(i & (DH_ - 1));
  int b = (int)(i >> 21);
  bf16x8 y = *(bf16x8*)(Yb + i);
  const float* nu = num + b * DH_ + h;
  const float* de = den + b * DH_ + h;
  float4 n0 = *(const float4*)nu;
  float4 n1 = *(const float4*)(nu + 4);
  float4 d0 = *(const float4*)de;
  float4 d1 = *(const float4*)(de + 4);
  bf16x8 o;
  o[0] = (bf16)((float)y[0] * n0.x / d0.x);
  o[1] = (bf16)((float)y[1] * n0.y / d0.y);
  o[2] = (bf16)((float)y[2] * n0.z / d0.z);
  o[3] = (bf16)((float)y[3] * n0.w / d0.w);
  o[4] = (bf16)((float)y[4] * n1.x / d1.x);
  o[5] = (bf16)((float)y[5] * n1.y / d1.y);
  o[6] = (bf16)((float)y[6] * n1.z / d1.z);
  o[7] = (bf16)((float)y[7] * n1.w / d1.w);
  *(bf16x8*)(Yb + i) = o;
}

// ---------------------------------------------------------------------------
extern "C" void kernel_launch(void* const* d_in, const int* in_sizes, int n_in,
                              void* d_out, int out_size, void* d_ws, size_t ws_size,
                              hipStream_t stream) {
  const float* q  = (const float*)d_in[0];
  const float* k  = (const float*)d_in[1];
  const float* v  = (const float*)d_in[2];
  const float* Wq = (const float*)d_in[3];
  const float* Wk = (const float*)d_in[4];
  const float* Wv = (const float*)d_in[5];
  const float* Wo = (const float*)d_in[6];
  // d_in[7] = W_bias mathematically unused (exp_pos_bias == all-ones).
  float* out = (float*)d_out;

  char* ws = (char*)d_ws;
  size_t off = 0;
  auto alloc = [&](size_t bytes) {
    char* p = ws + off;
    off += (bytes + 255) & ~(size_t)255;
    return p;
  };
  const size_t actN = (size_t)MROWS * DM_;   // 8388608
  const size_t wN   = (size_t)DH_ * DM_;     // 1048576

  bf16* Wqb = (bf16*)alloc(wN * 2);
  bf16* Wkb = (bf16*)alloc(wN * 2);
  bf16* Wvb = (bf16*)alloc(wN * 2);
  bf16* Wob = (bf16*)alloc(wN * 2);
  bf16* Kb  = (bf16*)alloc(actN * 2);
  bf16* Vb  = (bf16*)alloc(actN * 2);
  bf16* Yb  = (bf16*)alloc(actN * 2);
  float* part = (float*)alloc((size_t)256 * 8192 * 4);
  float* numden = (float*)alloc(8192 * 4);
  float* num = numden;
  float* den = numden + 4096;

  // 1) weights fp32 -> bf16 (activations convert inside gemm_f32a staging)
  CvtArgs ca;
  ca.job[0] = {Wq, Wqb, (int)(wN / 4)};
  ca.job[1] = {Wk, Wkb, (int)(wN / 4)};
  ca.job[2] = {Wv, Wvb, (int)(wN / 4)};
  ca.job[3] = {Wo, Wob, (int)(wN / 4)};
  cvt_kernel<<<dim3(wN / 4 / 2048, 4), 256, 0, stream>>>(ca);

  // 2) merged K/V/Q projections, fp32 A with register-prefetched staging
  GemmF32Args g1;
  g1.job[0] = {k, Wkb, Kb, 2};
  g1.job[1] = {v, Wvb, Vb, 2};
  g1.job[2] = {q, Wqb, Yb, 1};
  gemm_f32a<<<dim3(8, MROWS / 128, 3), 256, 0, stream>>>(g1);

  // 3) two-pass atomic-free reduction
  reduce_kv<<<dim3(256), 256, 0, stream>>>(Kb, Vb, part);
  finish_kv<<<dim3(64), 256, 0, stream>>>(part, numden);

  // 4) fold ratio into Y (in place)
  mul_ratio<<<dim3(actN / 8 / 256), 256, 0, stream>>>(Yb, num, den);

  // 5) out = Y' @ Wo^T
  GemmArgs g2;
  g2.N = DM_; g2.K = DH_;
  g2.job[0] = {Yb, Wob, out};
  gemm_bt<<<dim3(8, MROWS / 128, 1), 256, 0, stream>>>(g2);
}